// Round 8
// baseline (325.213 us; speedup 1.0000x reference)
//
#include <hip/hip_runtime.h>
#include <math.h>

#define D_MODEL 768
#define D_STATE 16
#define D_CONV  4
#define D_INNER 1536
#define BATCH   2
#define SEQ     512
#define M_ROWS  (BATCH * SEQ)            // 1024
#define N_XZ    (2 * D_INNER)            // 3072
#define N_XDBL  (D_INNER + 2 * D_STATE)  // 1568

typedef short  short8 __attribute__((ext_vector_type(8)));
typedef float  f32x4  __attribute__((ext_vector_type(4)));
typedef unsigned short ushort_t;
typedef ushort_t ushort8_t __attribute__((ext_vector_type(8)));

// ---- manual bf16 helpers (RNE), raw ushort storage ----
__device__ __forceinline__ ushort_t f2bf(float f) {
    unsigned int u = __float_as_uint(f);
    return (ushort_t)((u + 0x7fffu + ((u >> 16) & 1u)) >> 16);
}
__device__ __forceinline__ float bf2f(ushort_t s) {
    return __uint_as_float((unsigned int)s << 16);
}
__device__ __forceinline__ void split1(float x, ushort_t& h, ushort_t& l) {
    h = f2bf(x);
    l = f2bf(x - bf2f(h));
}
// split 8 consecutive fp32 -> interleaved [h0..h7][l0..l7] (32 B) at d
__device__ __forceinline__ void split8(const float* s, ushort_t* d) {
    ushort8_t h, l;
#pragma unroll
    for (int j = 0; j < 8; ++j) { ushort_t hh, ll; split1(s[j], hh, ll); h[j] = hh; l[j] = ll; }
    *(ushort8_t*)(d)     = h;
    *(ushort8_t*)(d + 8) = l;
}

// ---------------------------------------------------------------------------
// Fused split: x -> xs, W_in -> w1, W_x -> w2 (interleaved h|l layout).
// 8 elems/thread. Total elems = 786432 + 2359296 + 2408448 = 5554176 (exact).
// ---------------------------------------------------------------------------
#define SX  (M_ROWS * D_MODEL)
#define SW1 (N_XZ * D_MODEL)
#define SW2 (N_XDBL * D_INNER)
__global__ __launch_bounds__(256) void split3_kernel(
    const float* __restrict__ x, const float* __restrict__ win,
    const float* __restrict__ wx,
    ushort_t* __restrict__ xs, ushort_t* __restrict__ w1, ushort_t* __restrict__ w2)
{
    long i = ((long)blockIdx.x * 256 + threadIdx.x) * 8;
    const float* src; ushort_t* dst; long base;
    if (i < SX)            { src = x;   dst = xs; base = i; }
    else if (i < SX + SW1) { src = win; dst = w1; base = i - SX; }
    else                   { src = wx;  dst = w2; base = i - SX - SW1; }
    float v[8];
    *(float4*)(v)     = *(const float4*)(src + base);
    *(float4*)(v + 4) = *(const float4*)(src + base + 4);
    split8(v, dst + 2 * base);
}

// single-tensor split (interleaved), 8 elems/thread
__global__ __launch_bounds__(256) void split_kernel(
    const float* __restrict__ in, ushort_t* __restrict__ outp, long n)
{
    long i = ((long)blockIdx.x * 256 + threadIdx.x) * 8;
    if (i >= n) return;
    float v[8];
    *(float4*)(v)     = *(const float4*)(in + i);
    *(float4*)(v + 4) = *(const float4*)(in + i + 4);
    split8(v, outp + 2 * i);
}

// ---------------------------------------------------------------------------
// Split-bf16 MFMA GEMM — one wave per block, 64x64 tile, no LDS, no barriers,
// depth-2 register pipeline (VGPR~136 + 64 AGPR, fits; verified R7).
// Operands interleaved h|l: row r, elem k -> ushort off r*2K + 2k (h), +8 (l).
// XCD-compact swizzle: flat id f -> region (f&7)*R + (f>>3), decoded x-fastest,
// so each XCD (%8 round-robin heuristic) works a contiguous y-stripe whose
// working set fits its private 4 MB L2.
// NP = number of K-chunks (grid.z); chunk z stores fp32 partial to Cz.
// ---------------------------------------------------------------------------
template <int NP>
__global__ __launch_bounds__(64, 1) void gemm_mfma(
    const ushort_t* __restrict__ A, int lda,   // lda = K in elems
    const ushort_t* __restrict__ B, int ldb,
    float* __restrict__ C0, float* __restrict__ C1,
    float* __restrict__ C2, float* __restrict__ C3, int ldc,
    int N, int kc)
{
    const int Gx = gridDim.x, Gy = gridDim.y;
    const int T = Gx * Gy * gridDim.z;
    const int f = blockIdx.x + Gx * (blockIdx.y + Gy * blockIdx.z);
    const int R = T >> 3;
    const int g = (f & 7) * R + (f >> 3);
    const int bx = g % Gx;
    const int yz = g / Gx;
    const int by = yz % Gy;
    const int z  = yz / Gy;
    float* __restrict__ C = (NP <= 1 || z == 0) ? C0 :
                            (z == 1) ? C1 : (NP >= 3 && z == 2) ? C2 : C3;

    const int lane = threadIdx.x;
    const int bm = by * 64;
    const int bn = bx * 64;
    const int lr = lane & 15;
    const int lq = lane >> 4;
    const long kabs = (long)z * kc + lq * 8;

    long oA[4], oB[4];
#pragma unroll
    for (int i = 0; i < 4; ++i) {
        oA[i] = (long)(bm + i * 16 + lr) * (2 * lda) + 2 * kabs;
        int rB = bn + i * 16 + lr;
        if (rB >= N) rB = N - 1;               // clamp: in-buffer, discarded
        oB[i] = (long)rB * (2 * ldb) + 2 * kabs;
    }

    f32x4 acc[4][4] = {};
    short8 a0h[4], a0l[4], b0h[4], b0l[4];
    short8 a1h[4], a1l[4], b1h[4], b1l[4];

    auto loadset = [&](short8* ah, short8* al, short8* bh, short8* bl, int kk2) {
#pragma unroll
        for (int i = 0; i < 4; ++i) {
            ah[i] = *(const short8*)(A + oA[i] + kk2);
            al[i] = *(const short8*)(A + oA[i] + kk2 + 8);
            bh[i] = *(const short8*)(B + oB[i] + kk2);
            bl[i] = *(const short8*)(B + oB[i] + kk2 + 8);
        }
    };
    auto mfmaset = [&](short8* ah, short8* al, short8* bh, short8* bl) {
#pragma unroll
        for (int mt = 0; mt < 4; ++mt)
#pragma unroll
            for (int nt = 0; nt < 4; ++nt) {
                acc[mt][nt] = __builtin_amdgcn_mfma_f32_16x16x32_bf16(al[mt], bh[nt], acc[mt][nt], 0, 0, 0);
                acc[mt][nt] = __builtin_amdgcn_mfma_f32_16x16x32_bf16(ah[mt], bl[nt], acc[mt][nt], 0, 0, 0);
                acc[mt][nt] = __builtin_amdgcn_mfma_f32_16x16x32_bf16(ah[mt], bh[nt], acc[mt][nt], 0, 0, 0);
            }
    };

    const int nPair = kc >> 6;
    loadset(a0h, a0l, b0h, b0l, 0);
    int k2 = 0;                                 // ushort offset = 2*k
    for (int it = 0; it < nPair; ++it) {
        loadset(a1h, a1l, b1h, b1l, k2 + 64);   // in flight during MFMA set 0
        mfmaset(a0h, a0l, b0h, b0l);
        if (it + 1 < nPair)
            loadset(a0h, a0l, b0h, b0l, k2 + 128);
        mfmaset(a1h, a1l, b1h, b1l);
        k2 += 128;
    }

    // C/D layout: col = lane&15, row = (lane>>4)*4 + reg  [m89/m91]
    const int col0 = lane & 15;
    const int quad = lane >> 4;
#pragma unroll
    for (int mt = 0; mt < 4; ++mt)
#pragma unroll
        for (int nt = 0; nt < 4; ++nt)
#pragma unroll
            for (int r = 0; r < 4; ++r) {
                int row = bm + mt * 16 + quad * 4 + r;
                int col = bn + nt * 16 + col0;
                if (col >= N) continue;
                C[(long)row * ldc + col] = acc[mt][nt][r];
            }
}

// ---------------------------------------------------------------------------
// GEMM3 epilogue (3 partials): f = p0+p1+p2 -> xd interleaved split; cols >=
// 1536 also stored transposed fp32 into BCT. 8 elems/thread; p2 aliases xd
// region (same-thread read-before-write, no __restrict__ on that pair).
// ---------------------------------------------------------------------------
__global__ __launch_bounds__(256) void ep_xdbl_kernel(
    const float* __restrict__ p0, const float* __restrict__ p1,
    const float* p2, ushort_t* xd, float* __restrict__ BCT)
{
    long i = ((long)blockIdx.x * 256 + threadIdx.x) * 8;
    if (i >= (long)M_ROWS * N_XDBL) return;
    int row = (int)(i / N_XDBL);
    int col = (int)(i - (long)row * N_XDBL);    // multiple of 8
    float f[8];
#pragma unroll
    for (int j = 0; j < 8; ++j) f[j] = p0[i + j] + p1[i + j] + p2[i + j];
    split8(f, xd + 2 * i);
    if (col >= D_INNER) {
#pragma unroll
        for (int j = 0; j < 8; ++j)
            BCT[(long)(col + j - D_INNER) * M_ROWS + row] = f[j];
    }
}

// ---------------------------------------------------------------------------
// GEMM4 epilogue (4 partials): deltaT = softplus(sum + b_dt[row]).
// deltaT aliases p1 (same-index elementwise; no __restrict__ on that pair).
// ---------------------------------------------------------------------------
__global__ __launch_bounds__(256) void ep_softplus_kernel(
    const float* p0, const float* p1, const float* p2, const float* p3,
    const float* __restrict__ b_dt, float* deltaT)
{
    long i = ((long)blockIdx.x * 256 + threadIdx.x) * 8;
    if (i >= (long)D_INNER * M_ROWS) return;
    float b = b_dt[i >> 10];
    float o[8];
#pragma unroll
    for (int j = 0; j < 8; ++j) {
        float v = p0[i+j] + p1[i+j] + p2[i+j] + p3[i+j] + b;
        o[j] = fmaxf(v, 0.f) + log1pf(expf(-fabsf(v)));
    }
    *(float4*)(deltaT + i)     = *(float4*)(o);
    *(float4*)(deltaT + i + 4) = *(float4*)(o + 4);
}

// ---------------------------------------------------------------------------
// GEMM6 epilogue: out = p0+p1+p2+p3
// ---------------------------------------------------------------------------
__global__ __launch_bounds__(256) void ep_merge_kernel(
    const float* __restrict__ p0, const float* __restrict__ p1,
    const float* __restrict__ p2, const float* __restrict__ p3,
    float* __restrict__ out)
{
    long i = ((long)blockIdx.x * 256 + threadIdx.x) * 8;
    if (i >= (long)M_ROWS * D_MODEL) return;
    float o[8];
#pragma unroll
    for (int j = 0; j < 8; ++j) o[j] = p0[i+j] + p1[i+j] + p2[i+j] + p3[i+j];
    *(float4*)(out + i)     = *(float4*)(o);
    *(float4*)(out + i + 4) = *(float4*)(o + 4);
}

// ---------------------------------------------------------------------------
// Depthwise causal conv (width 4) + bias + SiLU.
// Outputs xconvT/zsiluT fp32 (transposed, for scan) and xc interleaved bf16.
// ---------------------------------------------------------------------------
__global__ __launch_bounds__(256) void conv_silu_kernel(
    const float* __restrict__ xz,
    const float* __restrict__ conv_w,
    const float* __restrict__ conv_b,
    float* __restrict__ xconvT,
    float* __restrict__ zsiluT,
    ushort_t* __restrict__ xc)
{
    int idx = blockIdx.x * blockDim.x + threadIdx.x;
    if (idx >= M_ROWS * D_INNER) return;
    int d = idx % D_INNER;
    int r = idx / D_INNER;
    int l = r % SEQ;
    float acc = conv_b[d];
#pragma unroll
    for (int k = 0; k < D_CONV; ++k) {
        if (l - (D_CONV - 1) + k >= 0)
            acc = fmaf(conv_w[d * D_CONV + k],
                       xz[(long)(r - (D_CONV - 1 - k)) * N_XZ + d], acc);
    }
    float s = acc / (1.f + expf(-acc));
    xconvT[(long)d * M_ROWS + r] = s;
    ushort_t h, lo;
    split1(s, h, lo);
    long off = (long)r * (2 * D_INNER) + ((d >> 3) * 16 + (d & 7));
    xc[off]     = h;
    xc[off + 8] = lo;
    float zv = xz[(long)r * N_XZ + D_INNER + d];
    zsiluT[(long)d * M_ROWS + r] = zv / (1.f + expf(-zv));
}

// ---------------------------------------------------------------------------
// Wave-per-(b,d) register scan. No LDS, no barriers. (verified R4-R7)
// ---------------------------------------------------------------------------
__global__ __launch_bounds__(256) void scan_kernel(
    const float* __restrict__ deltaT,
    const float* __restrict__ xconvT,
    const float* __restrict__ zsiluT,
    const float* __restrict__ BCT,     // (32, 1024)
    const float* __restrict__ A_log,
    const float* __restrict__ Dp,
    float* __restrict__ uT)
{
    const int bid = blockIdx.x;
    const int b   = bid / (D_INNER / 4);
    const int dg  = bid % (D_INNER / 4);
    const int tid = threadIdx.x;
    const int w   = tid >> 6;
    const int t   = tid & 63;
    const int d   = dg * 4 + w;
    const int base = b * SEQ;
    const int l0 = 8 * t;

    float dl[8], xr[8], yac[8];
#pragma unroll
    for (int i = 0; i < 8; ++i) {
        dl[i] = deltaT[(long)d * M_ROWS + base + l0 + i];
        xr[i] = xconvT[(long)d * M_ROWS + base + l0 + i];
        yac[i] = 0.f;
    }

    for (int n = 0; n < D_STATE; ++n) {
        const float Adn = -expf(A_log[d * D_STATE + n]);
        const float4* Bp = (const float4*)(BCT + (long)n * M_ROWS + base + l0);
        float4 b0 = Bp[0], b1 = Bp[1];
        float Bv[8] = {b0.x, b0.y, b0.z, b0.w, b1.x, b1.y, b1.z, b1.w};
        float c[8], v[8];
#pragma unroll
        for (int i = 0; i < 8; ++i) {
            c[i] = expf(dl[i] * Adn) + 1e-12f;
            v[i] = fabsf(dl[i] * Bv[i] * xr[i]) + 1e-12f;
        }
#pragma unroll
        for (int p = 0; p < 8; p += 2) { v[p+1] = fmaf(c[p+1], v[p+1], v[p]); c[p+1] *= c[p]; }
        v[3] = fmaf(c[3], v[3], v[1]); c[3] *= c[1];
        v[7] = fmaf(c[7], v[7], v[5]); c[7] *= c[5];
        v[7] = fmaf(c[7], v[7], v[3]); c[7] *= c[3];
        float c7 = c[7], v7 = v[7];
#pragma unroll
        for (int h = 1; h <= 32; h <<= 1) {
            float vl = __shfl_up(v7, (unsigned)h);
            float cl = __shfl_up(c7, (unsigned)h);
            bool right = ((t & (2 * h - 1)) == (2 * h - 1));
            if (right) { v7 = fmaf(c7, v7, vl); c7 *= cl; }
        }
#pragma unroll
        for (int h = 32; h >= 1; h >>= 1) {
            float vl = __shfl_up(v7, (unsigned)h);
            float vr = __shfl_down(v7, (unsigned)h);
            bool right = ((t & (2 * h - 1)) == (2 * h - 1));
            bool left  = ((t & (2 * h - 1)) == (h - 1));
            float nv = v7;
            if (right) nv = fmaf(c7, v7, vl);
            if (left)  nv = vr;
            v7 = nv;
        }
        v[7] = v7;
        c[7] = c7;
        float tmp;
        tmp = v[7]; v[7] = fmaf(c[7], v[7], v[3]); v[3] = tmp;
        tmp = v[3]; v[3] = fmaf(c[3], v[3], v[1]); v[1] = tmp;
        tmp = v[7]; v[7] = fmaf(c[7], v[7], v[5]); v[5] = tmp;
#pragma unroll
        for (int p = 0; p < 8; p += 2) {
            tmp = v[p+1]; v[p+1] = fmaf(c[p+1], v[p+1], v[p]); v[p] = tmp;
        }
        const float4* Cp = (const float4*)(BCT + (long)(16 + n) * M_ROWS + base + l0);
        float4 c0 = Cp[0], c1 = Cp[1];
        float Cv[8] = {c0.x, c0.y, c0.z, c0.w, c1.x, c1.y, c1.z, c1.w};
#pragma unroll
        for (int i = 0; i < 8; ++i) yac[i] = fmaf(v[i], Cv[i], yac[i]);
    }

    const float Dpd = Dp[d];
#pragma unroll
    for (int i = 0; i < 8; ++i) {
        float uv = fmaf(xr[i], Dpd, yac[i]) * zsiluT[(long)d * M_ROWS + base + l0 + i];
        uT[(long)d * M_ROWS + base + l0 + i] = uv;
    }
}

// ---------------------------------------------------------------------------
// Transpose + split: uT (1536,1024) fp32 -> u interleaved bf16 (1024,1536).
// ---------------------------------------------------------------------------
__global__ __launch_bounds__(256) void transpose_split_kernel(
    const float* __restrict__ uT, ushort_t* __restrict__ u)
{
    __shared__ float T[64][65];
    const int m0 = blockIdx.x * 64;
    const int d0 = blockIdx.y * 64;
    const int c  = threadIdx.x & 63;
    const int rr = threadIdx.x >> 6;
#pragma unroll
    for (int p = 0; p < 64; p += 4)
        T[p + rr][c] = uT[(long)(d0 + p + rr) * M_ROWS + m0 + c];
    __syncthreads();
#pragma unroll
    for (int p = 0; p < 64; p += 4) {
        int rm = p + rr;
        float v = T[c][rm];
        ushort_t h, l;
        split1(v, h, l);
        int d = d0 + c;
        long off = (long)(m0 + rm) * (2 * D_INNER) + ((d >> 3) * 16 + (d & 7));
        u[off]     = h;
        u[off + 8] = l;
    }
}

// ---------------------------------------------------------------------------
extern "C" void kernel_launch(void* const* d_in, const int* in_sizes, int n_in,
                              void* d_out, int out_size, void* d_ws, size_t ws_size,
                              hipStream_t stream)
{
    (void)in_sizes; (void)n_in; (void)out_size; (void)ws_size;

    const float* x      = (const float*)d_in[0];
    const float* W_in   = (const float*)d_in[1];
    const float* conv_w = (const float*)d_in[2];
    const float* conv_b = (const float*)d_in[3];
    const float* W_x    = (const float*)d_in[4];
    const float* W_dt   = (const float*)d_in[5];
    const float* b_dt   = (const float*)d_in[6];
    const float* A_log  = (const float*)d_in[7];
    const float* Dp     = (const float*)d_in[8];
    const float* W_out  = (const float*)d_in[9];
    float* out = (float*)d_out;

    // workspace (66.6 MB, same as R7). Alias plan:
    //  xz (12.58 MB): GEMM1 C -> conv input -> GEMM3 p1 -> GEMM4 p1/p2
    //    -> deltaT (lo) + uT (hi) -> u interleaved (lo)
    //  acc0 (6.42 MB): GEMM3 p0 -> GEMM4 p0 -> GEMM6 p0/p1
    //  xd region: GEMM3 p2 -> xd interleaved (GEMM4 B)
    //  xc region: conv out (GEMM3 A) -> GEMM4 p3 -> GEMM6 p2/p3
    float* ws = (float*)d_ws;
    long off = 0;
    float* xz     = ws + off; off += (long)M_ROWS * N_XZ;
    float* xz_lo  = xz;
    float* xz_hi  = xz + (long)D_INNER * M_ROWS;
    float* deltaT = xz_lo;
    float* uT     = xz_hi;
    ushort_t* u_i = (ushort_t*)xz_lo;                          // interleaved u
    float* xconvT = ws + off; off += (long)D_INNER * M_ROWS;
    float* zsiluT = ws + off; off += (long)D_INNER * M_ROWS;
    float* acc0   = ws + off; off += (long)M_ROWS * N_XDBL;
    ushort_t* w1  = (ushort_t*)(ws + off); off += (long)N_XZ * D_MODEL;    // interleaved
    ushort_t* w2  = (ushort_t*)(ws + off); off += (long)N_XDBL * D_INNER;  // interleaved
    ushort_t* xs  = (ushort_t*)(ws + off); off += (long)M_ROWS * D_MODEL;  // interleaved
    float* xcreg  = ws + off; off += (long)M_ROWS * D_INNER;               // xc / p-buf
    ushort_t* xc  = (ushort_t*)xcreg;
    float* xdreg  = ws + off; off += (long)M_ROWS * N_XDBL;                // p2 / xd
    ushort_t* xd  = (ushort_t*)xdreg;
    float* BCT    = ws + off; off += (long)2 * D_STATE * M_ROWS;

    dim3 blk(256);
    dim3 wblk(64);

    // splits: x, W_in, W_x in one launch
    hipLaunchKernelGGL(split3_kernel, dim3((SX + SW1 + SW2) / 2048), blk, 0, stream,
                       x, W_in, W_x, xs, w1, w2);
    // 1) xz = x @ W_in^T  (M=1024,N=3072,K=768), z=1, grid 768
    hipLaunchKernelGGL((gemm_mfma<1>), dim3(N_XZ / 64, M_ROWS / 64, 1), wblk, 0, stream,
                       xs, D_MODEL, w1, D_MODEL,
                       xz, xz, xz, xz, N_XZ, N_XZ, D_MODEL);
    // split W_dt -> w1 (W_in dead)
    hipLaunchKernelGGL(split_kernel, dim3((D_INNER * D_INNER) / 2048), blk, 0, stream,
                       W_dt, w1, (long)D_INNER * D_INNER);
    // 2) conv + silu
    hipLaunchKernelGGL(conv_silu_kernel, dim3((M_ROWS * D_INNER) / 256), blk, 0, stream,
                       xz, conv_w, conv_b, xconvT, zsiluT, xc);
    // 3) xconv @ W_x^T  (M=1024,N=1568,K=1536), z=3 (kc=512), grid 1200
    hipLaunchKernelGGL((gemm_mfma<3>), dim3((N_XDBL + 63) / 64, M_ROWS / 64, 3), wblk, 0, stream,
                       xc, D_INNER, w2, D_INNER,
                       acc0, xz, xdreg, xdreg, N_XDBL, N_XDBL, D_INNER / 3);
    hipLaunchKernelGGL(ep_xdbl_kernel, dim3((M_ROWS * N_XDBL) / 2048), blk, 0, stream,
                       acc0, xz, xdreg, xd, BCT);
    // split W_out -> w2 (W_x dead)
    hipLaunchKernelGGL(split_kernel, dim3((D_MODEL * D_INNER) / 2048), blk, 0, stream,
                       W_out, w2, (long)D_MODEL * D_INNER);
    // 4) W_dt @ x_dbl^T  (M=1536,N=1024,K=1536), z=4 (kc=384), grid 1536
    hipLaunchKernelGGL((gemm_mfma<4>), dim3(M_ROWS / 64, D_INNER / 64, 4), wblk, 0, stream,
                       w1, D_INNER, xd, N_XDBL,
                       acc0, xz_lo, xz_hi, xcreg, M_ROWS, M_ROWS, D_INNER / 4);
    hipLaunchKernelGGL(ep_softplus_kernel, dim3((D_INNER * M_ROWS) / 2048), blk, 0, stream,
                       acc0, xz_lo, xz_hi, xcreg, b_dt, deltaT);
    // 5) scan -> uT (xz_hi)
    hipLaunchKernelGGL(scan_kernel, dim3(BATCH * (D_INNER / 4)), blk, 0, stream,
                       deltaT, xconvT, zsiluT, BCT, A_log, Dp, uT);
    // 5b) transpose+split uT -> u interleaved (xz_lo; deltaT dead)
    hipLaunchKernelGGL(transpose_split_kernel, dim3(M_ROWS / 64, D_INNER / 64), blk, 0, stream,
                       uT, u_i);
    // 6) u @ W_out^T  (M=1024,N=768,K=1536), z=4 (kc=384), grid 768
    {
        float* p0 = acc0;
        float* p1 = acc0 + (long)M_ROWS * D_MODEL;
        float* p2 = xcreg;
        float* p3 = xcreg + (long)M_ROWS * D_MODEL;
        hipLaunchKernelGGL((gemm_mfma<4>), dim3(D_MODEL / 64, M_ROWS / 64, 4), wblk, 0, stream,
                           u_i, D_INNER, w2, D_INNER,
                           p0, p1, p2, p3, D_MODEL, D_MODEL, D_INNER / 4);
        hipLaunchKernelGGL(ep_merge_kernel, dim3((M_ROWS * D_MODEL) / 2048), blk, 0, stream,
                           p0, p1, p2, p3, out);
    }
}